// Round 8
// baseline (615.735 us; speedup 1.0000x reference)
//
#include <hip/hip_runtime.h>
#include <hip/hip_bf16.h>
#include <math.h>

#define T_TOK 8192
#define NE 1024
#define N_EXP 8
#define DFFN 2048
#define TW 16384        // total width = 8*2048
#define P_TOT 16384     // T_TOK * 2

#define TILE_M 256
#define TILE_N 256
#define BKT 32          // K-tile; 4 LDS buffers -> 3-deep prefetch

typedef __attribute__((ext_vector_type(8))) short bf16x8;
typedef __attribute__((ext_vector_type(4))) float f32x4;

#define GLOAD_LDS16(g, l) __builtin_amdgcn_global_load_lds( \
    (const __attribute__((address_space(1))) void*)(g), \
    (__attribute__((address_space(3))) void*)(l), 16, 0, 0)

static __device__ __forceinline__ unsigned short f2bf(float f) {
    __hip_bfloat16 b = __float2bfloat16(f);
    return *(unsigned short*)&b;
}

// ---------------------------------------------------------------------------
// Kernel A: router — logits, softmax, top-2, normalized weights, loss partials
// ---------------------------------------------------------------------------
__global__ __launch_bounds__(256) void router_kernel(
    const float* __restrict__ x, const float* __restrict__ wr,
    int* __restrict__ sel_idx, float* __restrict__ sel_wt,
    float* __restrict__ z_part, float* __restrict__ p_part)
{
    __shared__ float wrs[N_EXP * NE];   // 32 KB
    __shared__ float red[256];
    int tid = threadIdx.x;
    for (int i = tid; i < N_EXP * NE; i += 256) wrs[i] = wr[i];
    __syncthreads();

    int t = blockIdx.x * 256 + tid;   // T_TOK == 32*256 exactly
    float lg[N_EXP];
#pragma unroll
    for (int e = 0; e < N_EXP; e++) lg[e] = 0.f;

    const float4* x4 = (const float4*)(x + (size_t)t * NE);
    for (int n4 = 0; n4 < NE / 4; n4++) {
        float4 xv = x4[n4];
#pragma unroll
        for (int e = 0; e < N_EXP; e++) {
            const float* w = &wrs[e * NE + n4 * 4];
            lg[e] += xv.x * w[0] + xv.y * w[1] + xv.z * w[2] + xv.w * w[3];
        }
    }

    float m = lg[0];
#pragma unroll
    for (int e = 1; e < N_EXP; e++) m = fmaxf(m, lg[e]);
    float p[N_EXP], s = 0.f;
#pragma unroll
    for (int e = 0; e < N_EXP; e++) { p[e] = expf(lg[e] - m); s += p[e]; }
    float inv = 1.f / s;
#pragma unroll
    for (int e = 0; e < N_EXP; e++) p[e] *= inv;
    float lse = m + logf(s);

    int e0 = 0;
#pragma unroll
    for (int e = 1; e < N_EXP; e++) if (p[e] > p[e0]) e0 = e;
    int e1 = (e0 == 0) ? 1 : 0;
#pragma unroll
    for (int e = 0; e < N_EXP; e++) if (e != e0 && p[e] > p[e1]) e1 = e;

    float wn = 1.f / (p[e0] + p[e1]);
    sel_idx[t * 2 + 0] = e0;
    sel_idx[t * 2 + 1] = e1;
    sel_wt[t * 2 + 0] = p[e0] * wn;
    sel_wt[t * 2 + 1] = p[e1] * wn;

    red[tid] = lse * lse;
    __syncthreads();
    for (int st = 128; st > 0; st >>= 1) {
        if (tid < st) red[tid] += red[tid + st];
        __syncthreads();
    }
    if (tid == 0) z_part[blockIdx.x] = red[0];
#pragma unroll
    for (int e = 0; e < N_EXP; e++) {
        __syncthreads();
        red[tid] = p[e];
        __syncthreads();
        for (int st = 128; st > 0; st >>= 1) {
            if (tid < st) red[tid] += red[tid + st];
            __syncthreads();
        }
        if (tid == 0) p_part[blockIdx.x * N_EXP + e] = red[0];
    }
}

// ---------------------------------------------------------------------------
// Kernel B: counts (by scan), offsets, cursors, tile table, aux-loss outputs
// ---------------------------------------------------------------------------
__global__ __launch_bounds__(256) void finalize_router(
    const int* __restrict__ sel_idx,
    const float* __restrict__ z_part, const float* __restrict__ p_part,
    int* __restrict__ cnt, int* __restrict__ off, int* __restrict__ cursor,
    int* __restrict__ tile_tab, int* __restrict__ tile_n,
    float* __restrict__ out)
{
    __shared__ int redc[256];
    __shared__ int cnts[N_EXP];
    int tid = threadIdx.x;
    int c[N_EXP];
#pragma unroll
    for (int e = 0; e < N_EXP; e++) c[e] = 0;
    for (int i = tid; i < P_TOT; i += 256) c[sel_idx[i]]++;
#pragma unroll
    for (int e = 0; e < N_EXP; e++) {
        redc[tid] = c[e];
        __syncthreads();
        for (int st = 128; st > 0; st >>= 1) {
            if (tid < st) redc[tid] += redc[tid + st];
            __syncthreads();
        }
        if (tid == 0) cnts[e] = redc[0];
        __syncthreads();
    }
    if (tid == 0) {
        int o = 0;
        int nt = 0;
        for (int e = 0; e < N_EXP; e++) {
            cnt[e] = cnts[e];
            off[e] = o;
            o += cnts[e];
            cursor[e] = 0;
            for (int rb = 0; rb < cnts[e]; rb += TILE_M)
                tile_tab[nt++] = (e << 20) | rb;
        }
        off[N_EXP] = o;
        tile_n[0] = nt;
        float zs = 0.f;
        for (int b = 0; b < 32; b++) zs += z_part[b];
        float lb = 0.f;
        float* tail = out + (size_t)T_TOK * NE;
        for (int e = 0; e < N_EXP; e++) {
            float ps = 0.f;
            for (int b = 0; b < 32; b++) ps += p_part[b * N_EXP + e];
            float fi = (float)cnts[e] / (float)P_TOT;
            float pi = ps / (float)T_TOK;
            lb += fi * pi;
            tail[2 + e] = fi;
        }
        tail[0] = zs / (float)T_TOK;       // router_z_loss
        tail[1] = 8.f * lb;                // load_balance_loss
    }
}

// ---------------------------------------------------------------------------
// Kernel C: scatter (token,slot) pairs into per-expert lists
// ---------------------------------------------------------------------------
__global__ __launch_bounds__(256) void scatter_kernel(
    const int* __restrict__ sel_idx, const int* __restrict__ off,
    int* __restrict__ cursor, int* __restrict__ token_list)
{
    int i = blockIdx.x * 256 + threadIdx.x;
    if (i < P_TOT) {
        int e = sel_idx[i];
        int pos = atomicAdd(&cursor[e], 1);
        token_list[off[e] + pos] = i;   // token = i>>1, slot = i&1
    }
}

// ---------------------------------------------------------------------------
// Kernel G: gather + convert: xg[p,:] = bf16(x[tok(p),:]) (expert-sorted A)
// ---------------------------------------------------------------------------
__global__ __launch_bounds__(256) void gather_x_kernel(
    const float* __restrict__ x, const int* __restrict__ token_list,
    unsigned short* __restrict__ xg)
{
    int idx = blockIdx.x * 256 + threadIdx.x;
    int p = idx >> 7, c8 = (idx & 127) << 3;
    int tok = token_list[p] >> 1;
    const float4* s = (const float4*)(x + (size_t)tok * NE + c8);
    float4 v0 = s[0], v1 = s[1];
    ushort4 o0, o1;
    o0.x = f2bf(v0.x); o0.y = f2bf(v0.y); o0.z = f2bf(v0.z); o0.w = f2bf(v0.w);
    o1.x = f2bf(v1.x); o1.y = f2bf(v1.y); o1.z = f2bf(v1.z); o1.w = f2bf(v1.w);
    *(ushort4*)&xg[(size_t)p * NE + c8] = o0;
    *(ushort4*)&xg[(size_t)p * NE + c8 + 4] = o1;
}

// ---------------------------------------------------------------------------
// Kernel P2: transpose + convert: src [R][C] f32 -> dst [C][R] bf16
// ---------------------------------------------------------------------------
__global__ __launch_bounds__(256) void transpose_bf16_kernel(
    const float* __restrict__ src, unsigned short* __restrict__ dst,
    int R, int C)
{
    __shared__ float tile[64][65];
    int rb = blockIdx.y * 64, cb = blockIdx.x * 64;
    int tid = threadIdx.x;
#pragma unroll
    for (int p = 0; p < 4; p++) {
        int idx = p * 256 + tid;
        int r = idx >> 4, c4 = (idx & 15) << 2;
        float4 v = *(const float4*)&src[(size_t)(rb + r) * C + cb + c4];
        tile[r][c4 + 0] = v.x; tile[r][c4 + 1] = v.y;
        tile[r][c4 + 2] = v.z; tile[r][c4 + 3] = v.w;
    }
    __syncthreads();
#pragma unroll
    for (int p = 0; p < 4; p++) {
        int idx = p * 256 + tid;
        int c = idx >> 4, r4 = (idx & 15) << 2;
        ushort4 o;
        o.x = f2bf(tile[r4 + 0][c]); o.y = f2bf(tile[r4 + 1][c]);
        o.z = f2bf(tile[r4 + 2][c]); o.w = f2bf(tile[r4 + 3][c]);
        *(ushort4*)&dst[(size_t)(cb + c) * R + rb + r4] = o;
    }
}

// ---------------------------------------------------------------------------
// Deep-pipelined grouped GEMM core.
// 256x256 tile, BK=32, 8 waves (2M x 4N), per-wave 128x64 (acc[8][4]).
// FOUR LDS buffers (4 x (16KB A + 16KB B) = 128KB dynamic): stage tile t+3
// while computing tile t -> ~3 K-tile-times of load flight (covers HBM lat).
// Steady-state s_waitcnt vmcnt(12) (4 loads/wave/tile, 3 tiles in flight),
// peeled tail 8/4/0. One s_barrier pair per K-tile (vmcnt BEFORE barrier so
// the collective drain is complete when any wave proceeds).
// LDS layout chunk-major: elem = c*2048 + row*8 + (k&7)  (c = k>>3 within
// tile). ds_read_b128: 16-lane groups hit banks 4*row%32 -> 2-way (free);
// no swizzle needed. gload_lds granule g (1KB) = chunk g>>2, rows (g&3)*64,
// lane l -> row (g&3)*64+l: LDS-linear ✓, per-lane global src ✓.
// ---------------------------------------------------------------------------
#define STAGE_T(tt) do {                                                  \
    int _b = (tt) & 3;                                                    \
    size_t _kb = (size_t)(tt) * BKT;                                      \
    GLOAD_LDS16(srcA0 + _kb, Asm + _b * 8192 + dA0);                      \
    GLOAD_LDS16(srcA1 + _kb, Asm + _b * 8192 + dA1);                      \
    GLOAD_LDS16(srcB0 + _kb, Bsm + _b * 8192 + dB0);                      \
    GLOAD_LDS16(srcB1 + _kb, Bsm + _b * 8192 + dB1);                      \
} while (0)

#define COMPUTE_T(tt, VMI) do {                                           \
    asm volatile("s_waitcnt vmcnt(" VMI ")" ::: "memory");                \
    __builtin_amdgcn_s_barrier();                                         \
    __builtin_amdgcn_sched_barrier(0);                                    \
    const __hip_bfloat16* Ac = Asm + ((tt) & 3) * 8192;                   \
    const __hip_bfloat16* Bc = Bsm + ((tt) & 3) * 8192;                   \
    bf16x8 af[8], bfr[4];                                                 \
    _Pragma("unroll")                                                     \
    for (int m = 0; m < 8; m++) af[m] = *(const bf16x8*)&Ac[aoff[m]];     \
    _Pragma("unroll")                                                     \
    for (int n = 0; n < 4; n++) bfr[n] = *(const bf16x8*)&Bc[boff[n]];    \
    _Pragma("unroll")                                                     \
    for (int m = 0; m < 8; m++)                                           \
        _Pragma("unroll")                                                 \
        for (int n = 0; n < 4; n++)                                       \
            acc[m][n] = __builtin_amdgcn_mfma_f32_16x16x32_bf16(          \
                af[m], bfr[n], acc[m][n], 0, 0, 0);                       \
    __builtin_amdgcn_s_barrier();                                         \
} while (0)

#define GEMM_SETUP()                                                      \
    int tid = threadIdx.x;                                                \
    int wid = tid >> 6, lane = tid & 63;                                  \
    int wm = wid >> 2, wn = wid & 3;                                      \
    int rr = lane & 15, kq = lane >> 4;                                   \
    int g0 = 2 * wid, g1 = 2 * wid + 1;                                   \
    int c0 = g0 >> 2, rb0 = g0 & 3;                                       \
    int c1 = g1 >> 2, rb1 = g1 & 3;                                       \
    int dA0 = g0 * 512, dA1 = g1 * 512, dB0 = g0 * 512, dB1 = g1 * 512;   \
    int aoff[8], boff[4];                                                 \
    _Pragma("unroll")                                                     \
    for (int m = 0; m < 8; m++) aoff[m] = kq * 2048 + (wm * 128 + m * 16 + rr) * 8; \
    _Pragma("unroll")                                                     \
    for (int n = 0; n < 4; n++) boff[n] = kq * 2048 + (wn * 64 + n * 16 + rr) * 8;

// ---------------------------------------------------------------------------
// Kernel D: grouped GEMM1:  h[p,:] = selw[p] * gelu(xg[p,:] @ W1_e)
// grid = 576 (1-D): f -> col-tile yc = f&7 (one per XCD), row-tile xt = f>>3
// ---------------------------------------------------------------------------
__global__ __launch_bounds__(512, 1) void gemm1_mfma(
    const __hip_bfloat16* __restrict__ xg, const __hip_bfloat16* __restrict__ w1t,
    const int* __restrict__ token_list, const float* __restrict__ sel_wt,
    const int* __restrict__ cnt, const int* __restrict__ off,
    const int* __restrict__ tile_tab, const int* __restrict__ tile_n,
    __hip_bfloat16* __restrict__ h)
{
    extern __shared__ __align__(16) __hip_bfloat16 smem[];
    __hip_bfloat16* Asm = smem;            // 4 bufs x 8192 elems
    __hip_bfloat16* Bsm = smem + 32768;

    int f = blockIdx.x;
    int xt = f >> 3, yc = f & 7;
    if (xt >= tile_n[0]) return;
    int tab = tile_tab[xt];
    int e = tab >> 20, rowbase = tab & 0xFFFFF;
    int off_e = off[e];
    int rows_e = cnt[e] - rowbase;
    int colbase = yc * TILE_N;

    GEMM_SETUP()

    int rA0 = rb0 * 64 + lane, rA1 = rb1 * 64 + lane;
    const __hip_bfloat16* srcA0 = xg + ((size_t)off_e + rowbase + ((rA0 < rows_e) ? rA0 : 0)) * NE + c0 * 8;
    const __hip_bfloat16* srcA1 = xg + ((size_t)off_e + rowbase + ((rA1 < rows_e) ? rA1 : 0)) * NE + c1 * 8;
    const __hip_bfloat16* srcB0 = w1t + ((size_t)e * DFFN + colbase + rb0 * 64 + lane) * NE + c0 * 8;
    const __hip_bfloat16* srcB1 = w1t + ((size_t)e * DFFN + colbase + rb1 * 64 + lane) * NE + c1 * 8;

    f32x4 acc[8][4] = {};
    const int NKT = NE / BKT;   // 32
    STAGE_T(0); STAGE_T(1); STAGE_T(2);
    for (int t = 0; t < NKT - 3; t++) {
        STAGE_T(t + 3);
        COMPUTE_T(t, "12");
    }
    COMPUTE_T(NKT - 3, "8");
    COMPUTE_T(NKT - 2, "4");
    COMPUTE_T(NKT - 1, "0");

    int colg = colbase + wn * 64;
#pragma unroll
    for (int m = 0; m < 8; m++) {
#pragma unroll
        for (int j = 0; j < 4; j++) {
            int r = wm * 128 + m * 16 + kq * 4 + j;
            if (r < rows_e) {
                size_t p = (size_t)off_e + rowbase + r;
                float wgt = sel_wt[token_list[p]];
#pragma unroll
                for (int n = 0; n < 4; n++) {
                    float v = acc[m][n][j];
                    float g = 0.5f * v * (1.f + erff(v * 0.70710678118f));
                    h[p * DFFN + colg + n * 16 + rr] = __float2bfloat16(wgt * g);
                }
            }
        }
    }
}

// ---------------------------------------------------------------------------
// Kernel E: grouped GEMM2:  out[tok(p),:] += h[p,:] @ W2_e  (atomic f32; no
// split-K: exactly 2 commutative addends per element -> deterministic)
// grid = 288 (1-D): yc = (f&7)>>1 (2 XCDs per col-tile), xt = (f>>3)*2+(f&1)
// ---------------------------------------------------------------------------
__global__ __launch_bounds__(512, 1) void gemm2_mfma(
    const __hip_bfloat16* __restrict__ h, const __hip_bfloat16* __restrict__ w2t,
    const int* __restrict__ token_list,
    const int* __restrict__ cnt, const int* __restrict__ off,
    const int* __restrict__ tile_tab, const int* __restrict__ tile_n,
    float* __restrict__ out)
{
    extern __shared__ __align__(16) __hip_bfloat16 smem[];
    __hip_bfloat16* Asm = smem;
    __hip_bfloat16* Bsm = smem + 32768;

    int f = blockIdx.x;
    int yc = (f & 7) >> 1;
    int xt = (f >> 3) * 2 + (f & 1);
    if (xt >= tile_n[0]) return;
    int tab = tile_tab[xt];
    int e = tab >> 20, rowbase = tab & 0xFFFFF;
    int off_e = off[e];
    int rows_e = cnt[e] - rowbase;
    int colbase = yc * TILE_N;

    GEMM_SETUP()

    int rA0 = rb0 * 64 + lane, rA1 = rb1 * 64 + lane;
    const __hip_bfloat16* srcA0 = h + ((size_t)off_e + rowbase + ((rA0 < rows_e) ? rA0 : 0)) * DFFN + c0 * 8;
    const __hip_bfloat16* srcA1 = h + ((size_t)off_e + rowbase + ((rA1 < rows_e) ? rA1 : 0)) * DFFN + c1 * 8;
    const __hip_bfloat16* srcB0 = w2t + ((size_t)colbase + rb0 * 64 + lane) * TW + e * DFFN + c0 * 8;
    const __hip_bfloat16* srcB1 = w2t + ((size_t)colbase + rb1 * 64 + lane) * TW + e * DFFN + c1 * 8;

    f32x4 acc[8][4] = {};
    const int NKT = DFFN / BKT;   // 64
    STAGE_T(0); STAGE_T(1); STAGE_T(2);
    for (int t = 0; t < NKT - 3; t++) {
        STAGE_T(t + 3);
        COMPUTE_T(t, "12");
    }
    COMPUTE_T(NKT - 3, "8");
    COMPUTE_T(NKT - 2, "4");
    COMPUTE_T(NKT - 1, "0");

    int colg = colbase + wn * 64;
#pragma unroll
    for (int m = 0; m < 8; m++) {
#pragma unroll
        for (int j = 0; j < 4; j++) {
            int r = wm * 128 + m * 16 + kq * 4 + j;
            if (r < rows_e) {
                size_t p = (size_t)off_e + rowbase + r;
                int tok = token_list[p] >> 1;
#pragma unroll
                for (int n = 0; n < 4; n++)
                    atomicAdd(&out[(size_t)tok * NE + colg + n * 16 + rr],
                              acc[m][n][j]);
            }
        }
    }
}

// ---------------------------------------------------------------------------
extern "C" void kernel_launch(void* const* d_in, const int* in_sizes, int n_in,
                              void* d_out, int out_size, void* d_ws, size_t ws_size,
                              hipStream_t stream)
{
    const float* x  = (const float*)d_in[0];
    const float* wr = (const float*)d_in[1];
    const float* w1 = (const float*)d_in[2];
    const float* w2 = (const float*)d_in[3];
    float* out = (float*)d_out;

    // workspace layout (~168 MB)
    char* ws = (char*)d_ws;
    size_t o = 0;
    __hip_bfloat16* h   = (__hip_bfloat16*)(ws + o); o += (size_t)P_TOT * DFFN * 2;  // 67.1MB
    __hip_bfloat16* xg  = (__hip_bfloat16*)(ws + o); o += (size_t)P_TOT * NE * 2;    // 33.6MB
    __hip_bfloat16* w1t = (__hip_bfloat16*)(ws + o); o += (size_t)NE * TW * 2;       // 33.6MB  [TW][NE]
    __hip_bfloat16* w2t = (__hip_bfloat16*)(ws + o); o += (size_t)TW * NE * 2;       // 33.6MB  [NE][TW]
    int*   sel_idx    = (int*)(ws + o);   o += P_TOT * 4;
    float* sel_wt     = (float*)(ws + o); o += P_TOT * 4;
    int*   token_list = (int*)(ws + o);   o += P_TOT * 4;
    int*   cnt        = (int*)(ws + o);   o += 64;
    int*   off        = (int*)(ws + o);   o += 64;
    int*   cursor     = (int*)(ws + o);   o += 64;
    int*   tile_tab   = (int*)(ws + o);   o += 256 * 4;
    int*   tile_n     = (int*)(ws + o);   o += 64;
    float* z_part     = (float*)(ws + o); o += 32 * 4;
    float* p_part     = (float*)(ws + o); o += 32 * N_EXP * 4;

    hipFuncSetAttribute((const void*)gemm1_mfma,
                        hipFuncAttributeMaxDynamicSharedMemorySize, 131072);
    hipFuncSetAttribute((const void*)gemm2_mfma,
                        hipFuncAttributeMaxDynamicSharedMemorySize, 131072);

    hipMemsetAsync(d_out, 0, (size_t)out_size * sizeof(float), stream);

    router_kernel<<<32, 256, 0, stream>>>(x, wr, sel_idx, sel_wt, z_part, p_part);
    finalize_router<<<1, 256, 0, stream>>>(sel_idx, z_part, p_part, cnt, off, cursor,
                                           tile_tab, tile_n, out);
    scatter_kernel<<<64, 256, 0, stream>>>(sel_idx, off, cursor, token_list);
    gather_x_kernel<<<P_TOT * (NE / 8) / 256, 256, 0, stream>>>(x, token_list,
                                                                (unsigned short*)xg);
    transpose_bf16_kernel<<<dim3(TW / 64, NE / 64), 256, 0, stream>>>(
        w1, (unsigned short*)w1t, NE, TW);     // w1 [NE][TW] -> w1t [TW][NE]
    transpose_bf16_kernel<<<dim3(NE / 64, TW / 64), 256, 0, stream>>>(
        w2, (unsigned short*)w2t, TW, NE);     // w2 [TW][NE] -> w2t [NE][TW]

    // gemm1: 72 row-tile slots x 8 col-tiles = 576; gemm2: 72 x 4 = 288
    gemm1_mfma<<<576, 512, 131072, stream>>>(
        xg, w1t, token_list, sel_wt, cnt, off, tile_tab, tile_n, h);
    gemm2_mfma<<<288, 512, 131072, stream>>>(
        h, w2t, token_list, cnt, off, tile_tab, tile_n, out);
}

// Round 9
// 455.496 us; speedup vs baseline: 1.3518x; 1.3518x over previous
//
#include <hip/hip_runtime.h>
#include <hip/hip_bf16.h>
#include <math.h>

#define T_TOK 8192
#define NE 1024
#define N_EXP 8
#define DFFN 2048
#define TW 16384        // total width = 8*2048
#define P_TOT 16384     // T_TOK * 2

#define BMT 128
#define BNT 128
#define BK9 32

typedef __attribute__((ext_vector_type(8))) short bf16x8;
typedef __attribute__((ext_vector_type(4))) float f32x4;

#define GLOAD_LDS16(g, l) __builtin_amdgcn_global_load_lds( \
    (const __attribute__((address_space(1))) void*)(g), \
    (__attribute__((address_space(3))) void*)(l), 16, 0, 0)

static __device__ __forceinline__ unsigned short f2bf(float f) {
    __hip_bfloat16 b = __float2bfloat16(f);
    return *(unsigned short*)&b;
}

// fast exact-enough gelu: 0.5x(1+tanh(√(2/π)(x+0.044715x³))) = x·sigmoid(2u)
static __device__ __forceinline__ float gelu_fast(float v) {
    float u2 = v * (1.5957691216f + 0.0713548162f * v * v);   // 2u
    return v / (1.f + __expf(-u2));
}

// ---------------------------------------------------------------------------
// Kernel A: router — 8 lanes per token, 256 blocks (was 32: latency-bound).
// f32 throughout (bf16 logits would flip near-tie top-k selections).
// ---------------------------------------------------------------------------
__global__ __launch_bounds__(256) void router_kernel(
    const float* __restrict__ x, const float* __restrict__ wr,
    int* __restrict__ sel_idx, float* __restrict__ sel_wt,
    float* __restrict__ z_part, float* __restrict__ p_part)
{
    __shared__ float wrs[N_EXP * NE];   // 32 KB
    __shared__ float zred[32];
    __shared__ float pred[32][8];
    int tid = threadIdx.x;
    for (int i = tid; i < N_EXP * NE / 4; i += 256)
        ((float4*)wrs)[i] = ((const float4*)wr)[i];
    __syncthreads();

    int slot = tid >> 3, oct = tid & 7;
    int t = blockIdx.x * 32 + slot;          // 256 blocks x 32 tokens
    float lg[N_EXP];
#pragma unroll
    for (int e = 0; e < N_EXP; e++) lg[e] = 0.f;

    const float4* x4 = (const float4*)(x + (size_t)t * NE) + oct * 32;
    for (int n4 = 0; n4 < 32; n4++) {
        float4 xv = x4[n4];
#pragma unroll
        for (int e = 0; e < N_EXP; e++) {
            const float* w = &wrs[e * NE + oct * 128 + n4 * 4];
            lg[e] += xv.x * w[0] + xv.y * w[1] + xv.z * w[2] + xv.w * w[3];
        }
    }
#pragma unroll
    for (int d = 1; d < 8; d <<= 1)
#pragma unroll
        for (int e = 0; e < N_EXP; e++) lg[e] += __shfl_xor(lg[e], d);

    float m = lg[0];
#pragma unroll
    for (int e = 1; e < N_EXP; e++) m = fmaxf(m, lg[e]);
    float p[N_EXP], s = 0.f;
#pragma unroll
    for (int e = 0; e < N_EXP; e++) { p[e] = expf(lg[e] - m); s += p[e]; }
    float inv = 1.f / s;
#pragma unroll
    for (int e = 0; e < N_EXP; e++) p[e] *= inv;
    float lse = m + logf(s);

    int e0 = 0;
#pragma unroll
    for (int e = 1; e < N_EXP; e++) if (p[e] > p[e0]) e0 = e;
    int e1 = (e0 == 0) ? 1 : 0;
#pragma unroll
    for (int e = 0; e < N_EXP; e++) if (e != e0 && p[e] > p[e1]) e1 = e;

    if (oct == 0) {
        float wn = 1.f / (p[e0] + p[e1]);
        sel_idx[t * 2 + 0] = e0;
        sel_idx[t * 2 + 1] = e1;
        sel_wt[t * 2 + 0] = p[e0] * wn;
        sel_wt[t * 2 + 1] = p[e1] * wn;
        zred[slot] = lse * lse;
#pragma unroll
        for (int e = 0; e < N_EXP; e++) pred[slot][e] = p[e];
    }
    __syncthreads();
    if (tid == 0) {
        float zs = 0.f;
        for (int i = 0; i < 32; i++) zs += zred[i];
        z_part[blockIdx.x] = zs;
        for (int e = 0; e < N_EXP; e++) {
            float ps = 0.f;
            for (int i = 0; i < 32; i++) ps += pred[i][e];
            p_part[blockIdx.x * N_EXP + e] = ps;
        }
    }
}

// ---------------------------------------------------------------------------
// Kernel B: counts (by scan), offsets, cursors, tile table, aux-loss outputs
// ---------------------------------------------------------------------------
__global__ __launch_bounds__(256) void finalize_router(
    const int* __restrict__ sel_idx,
    const float* __restrict__ z_part, const float* __restrict__ p_part,
    int* __restrict__ cnt, int* __restrict__ off, int* __restrict__ cursor,
    int* __restrict__ tile_tab, int* __restrict__ tile_n,
    float* __restrict__ out)
{
    __shared__ int redc[256];
    __shared__ int cnts[N_EXP];
    int tid = threadIdx.x;
    int c[N_EXP];
#pragma unroll
    for (int e = 0; e < N_EXP; e++) c[e] = 0;
    for (int i = tid; i < P_TOT; i += 256) c[sel_idx[i]]++;
#pragma unroll
    for (int e = 0; e < N_EXP; e++) {
        redc[tid] = c[e];
        __syncthreads();
        for (int st = 128; st > 0; st >>= 1) {
            if (tid < st) redc[tid] += redc[tid + st];
            __syncthreads();
        }
        if (tid == 0) cnts[e] = redc[0];
        __syncthreads();
    }
    if (tid == 0) {
        int o = 0;
        int nt = 0;
        for (int e = 0; e < N_EXP; e++) {
            cnt[e] = cnts[e];
            off[e] = o;
            o += cnts[e];
            cursor[e] = 0;
            for (int rb = 0; rb < cnts[e]; rb += BMT)
                tile_tab[nt++] = (e << 20) | rb;
        }
        off[N_EXP] = o;
        tile_n[0] = nt;
        float zs = 0.f;
        for (int b = 0; b < 256; b++) zs += z_part[b];
        float lb = 0.f;
        float* tail = out + (size_t)T_TOK * NE;
        for (int e = 0; e < N_EXP; e++) {
            float ps = 0.f;
            for (int b = 0; b < 256; b++) ps += p_part[b * N_EXP + e];
            float fi = (float)cnts[e] / (float)P_TOT;
            float pi = ps / (float)T_TOK;
            lb += fi * pi;
            tail[2 + e] = fi;
        }
        tail[0] = zs / (float)T_TOK;       // router_z_loss
        tail[1] = 8.f * lb;                // load_balance_loss
    }
}

// ---------------------------------------------------------------------------
// Kernel C: scatter (token,slot) pairs into per-expert lists
// ---------------------------------------------------------------------------
__global__ __launch_bounds__(256) void scatter_kernel(
    const int* __restrict__ sel_idx, const int* __restrict__ off,
    int* __restrict__ cursor, int* __restrict__ token_list)
{
    int i = blockIdx.x * 256 + threadIdx.x;
    if (i < P_TOT) {
        int e = sel_idx[i];
        int pos = atomicAdd(&cursor[e], 1);
        token_list[off[e] + pos] = i;   // token = i>>1, slot = i&1
    }
}

// ---------------------------------------------------------------------------
// Kernel P1: x f32 -> bf16 (same layout; gemm1 gathers per-lane from xb)
// ---------------------------------------------------------------------------
__global__ __launch_bounds__(256) void cvt_x_kernel(
    const float* __restrict__ x, unsigned short* __restrict__ xb)
{
    int i = blockIdx.x * 256 + threadIdx.x;     // one float4 per thread
    float4 v = ((const float4*)x)[i];
    ushort4 o;
    o.x = f2bf(v.x); o.y = f2bf(v.y); o.z = f2bf(v.z); o.w = f2bf(v.w);
    ((ushort4*)xb)[i] = o;
}

// ---------------------------------------------------------------------------
// Kernel P2: transpose + convert: src [R][C] f32 -> dst [C][R] bf16
// ---------------------------------------------------------------------------
__global__ __launch_bounds__(256) void transpose_bf16_kernel(
    const float* __restrict__ src, unsigned short* __restrict__ dst,
    int R, int C)
{
    __shared__ float tile[64][65];
    int rb = blockIdx.y * 64, cb = blockIdx.x * 64;
    int tid = threadIdx.x;
#pragma unroll
    for (int p = 0; p < 4; p++) {
        int idx = p * 256 + tid;
        int r = idx >> 4, c4 = (idx & 15) << 2;
        float4 v = *(const float4*)&src[(size_t)(rb + r) * C + cb + c4];
        tile[r][c4 + 0] = v.x; tile[r][c4 + 1] = v.y;
        tile[r][c4 + 2] = v.z; tile[r][c4 + 3] = v.w;
    }
    __syncthreads();
#pragma unroll
    for (int p = 0; p < 4; p++) {
        int idx = p * 256 + tid;
        int c = idx >> 4, r4 = (idx & 15) << 2;
        ushort4 o;
        o.x = f2bf(tile[r4 + 0][c]); o.y = f2bf(tile[r4 + 1][c]);
        o.z = f2bf(tile[r4 + 2][c]); o.w = f2bf(tile[r4 + 3][c]);
        *(ushort4*)&dst[(size_t)(cb + c) * R + rb + r4] = o;
    }
}

// ---------------------------------------------------------------------------
// GEMM core (R4-swizzle + R6-counted-vmcnt, HIGH OCCUPANCY):
// 128x128 tile, BK=32, 4 waves (2x2), per-wave 64x64 (acc[4][4]).
// LDS = 32 KB dbuf, VGPR capped by __launch_bounds__(256,4) -> 4 blocks/CU
// (16 waves/CU): cross-block TLP hides each block's barrier/vmcnt stalls
// (the m97/m114 mechanism). Counted vmcnt(4): next tile's 4 loads stay in
// flight across the barrier; drain to 0 only on the last iteration.
// Zero-conflict XOR swizzle (measured 0 in R4/R5): source chunk
// ksw=(lane&3)^((lane>>3)&3); read slot kqa=kq^((rr>>1)&3).
// ---------------------------------------------------------------------------
#define STG(buf, kb) do {                                                 \
    GLOAD_LDS16(asrc0 + (kb), &As[buf][wid * 1024]);                      \
    GLOAD_LDS16(asrc1 + (kb), &As[buf][wid * 1024 + 512]);                \
    GLOAD_LDS16(bsrc0 + (kb), &Bs[buf][wid * 1024]);                      \
    GLOAD_LDS16(bsrc1 + (kb), &Bs[buf][wid * 1024 + 512]);                \
} while (0)

#define GEMM_LOOP(NKT)                                                    \
    STG(0, 0);                                                            \
    for (int t = 0; t < (NKT); t++) {                                     \
        int cur = t & 1;                                                  \
        if (t + 1 < (NKT)) {                                              \
            STG(cur ^ 1, (t + 1) * BK9);                                  \
            asm volatile("s_waitcnt vmcnt(4)" ::: "memory");              \
        } else {                                                          \
            asm volatile("s_waitcnt vmcnt(0)" ::: "memory");              \
        }                                                                 \
        __builtin_amdgcn_s_barrier();                                     \
        __builtin_amdgcn_sched_barrier(0);                                \
        bf16x8 af[4], bfr[4];                                             \
        _Pragma("unroll")                                                 \
        for (int m = 0; m < 4; m++)                                       \
            af[m] = *(const bf16x8*)&As[cur][(wm * 64 + m * 16 + rr) * BK9 + kqa * 8]; \
        _Pragma("unroll")                                                 \
        for (int n = 0; n < 4; n++)                                       \
            bfr[n] = *(const bf16x8*)&Bs[cur][(wn * 64 + n * 16 + rr) * BK9 + kqa * 8]; \
        _Pragma("unroll")                                                 \
        for (int m = 0; m < 4; m++)                                       \
            _Pragma("unroll")                                             \
            for (int n = 0; n < 4; n++)                                   \
                acc[m][n] = __builtin_amdgcn_mfma_f32_16x16x32_bf16(      \
                    af[m], bfr[n], acc[m][n], 0, 0, 0);                   \
        __builtin_amdgcn_sched_barrier(0);                                \
        __builtin_amdgcn_s_barrier();                                     \
    }

// ---------------------------------------------------------------------------
// Kernel D: grouped GEMM1:  h[p,:] = selw[p] * gelu(xb[tok(p),:] @ W1_e)
// ---------------------------------------------------------------------------
__global__ __launch_bounds__(256, 4) void gemm1_mfma(
    const __hip_bfloat16* __restrict__ xb, const __hip_bfloat16* __restrict__ w1t,
    const int* __restrict__ token_list, const float* __restrict__ sel_wt,
    const int* __restrict__ cnt, const int* __restrict__ off,
    const int* __restrict__ tile_tab, const int* __restrict__ tile_n,
    __hip_bfloat16* __restrict__ h)
{
    __shared__ __align__(16) __hip_bfloat16 As[2][BMT * BK9];   // 16 KB
    __shared__ __align__(16) __hip_bfloat16 Bs[2][BNT * BK9];   // 16 KB

    int flat = blockIdx.x;
    if (flat >= tile_n[0]) return;
    int tab = tile_tab[flat];
    int e = tab >> 20, rowbase = tab & 0xFFFFF;
    int off_e = off[e];
    int rows_e = cnt[e] - rowbase;
    int colbase = blockIdx.y * BNT;

    int tid = threadIdx.x;
    int wid = tid >> 6, lane = tid & 63;
    int wm = wid >> 1, wn = wid & 1;
    int rr = lane & 15, kq = lane >> 4;
    int kqa = kq ^ ((rr >> 1) & 3);
    int ksw = (lane & 3) ^ ((lane >> 3) & 3);

    // staging: wave wid owns granules 2wid,2wid+1 (rows wid*32..wid*32+31)
    int r0 = wid * 32 + (lane >> 2);
    int r1 = r0 + 16;
    int ent0 = token_list[off_e + rowbase + ((r0 < rows_e) ? r0 : 0)];
    int ent1 = token_list[off_e + rowbase + ((r1 < rows_e) ? r1 : 0)];
    const __hip_bfloat16* asrc0 = xb + (size_t)(ent0 >> 1) * NE + ksw * 8;
    const __hip_bfloat16* asrc1 = xb + (size_t)(ent1 >> 1) * NE + ksw * 8;
    const __hip_bfloat16* bsrc0 = w1t + (size_t)(e * DFFN + colbase + r0) * NE + ksw * 8;
    const __hip_bfloat16* bsrc1 = bsrc0 + (size_t)16 * NE;

    f32x4 acc[4][4] = {};
    GEMM_LOOP(NE / BK9)

    int colg = colbase + wn * 64;
#pragma unroll
    for (int m = 0; m < 4; m++) {
#pragma unroll
        for (int j = 0; j < 4; j++) {
            int r = wm * 64 + m * 16 + kq * 4 + j;
            if (r < rows_e) {
                size_t p = (size_t)off_e + rowbase + r;
                float wgt = sel_wt[token_list[p]];
#pragma unroll
                for (int n = 0; n < 4; n++) {
                    float g = gelu_fast(acc[m][n][j]);
                    h[p * DFFN + colg + n * 16 + rr] = __float2bfloat16(wgt * g);
                }
            }
        }
    }
}

// ---------------------------------------------------------------------------
// Kernel E: grouped GEMM2:  out[tok(p),:] += h[p,:] @ W2_e  (atomic f32;
// exactly 2 commutative addends per element -> deterministic)
// ---------------------------------------------------------------------------
__global__ __launch_bounds__(256, 4) void gemm2_mfma(
    const __hip_bfloat16* __restrict__ h, const __hip_bfloat16* __restrict__ w2t,
    const int* __restrict__ token_list,
    const int* __restrict__ cnt, const int* __restrict__ off,
    const int* __restrict__ tile_tab, const int* __restrict__ tile_n,
    float* __restrict__ out)
{
    __shared__ __align__(16) __hip_bfloat16 As[2][BMT * BK9];
    __shared__ __align__(16) __hip_bfloat16 Bs[2][BNT * BK9];

    int flat = blockIdx.x;
    if (flat >= tile_n[0]) return;
    int tab = tile_tab[flat];
    int e = tab >> 20, rowbase = tab & 0xFFFFF;
    int off_e = off[e];
    int rows_e = cnt[e] - rowbase;
    int colbase = blockIdx.y * BNT;

    int tid = threadIdx.x;
    int wid = tid >> 6, lane = tid & 63;
    int wm = wid >> 1, wn = wid & 1;
    int rr = lane & 15, kq = lane >> 4;
    int kqa = kq ^ ((rr >> 1) & 3);
    int ksw = (lane & 3) ^ ((lane >> 3) & 3);

    int r0 = wid * 32 + (lane >> 2);
    int r1 = r0 + 16;
    int pr0 = off_e + rowbase + ((r0 < rows_e) ? r0 : 0);
    int pr1 = off_e + rowbase + ((r1 < rows_e) ? r1 : 0);
    const __hip_bfloat16* asrc0 = h + (size_t)pr0 * DFFN + ksw * 8;
    const __hip_bfloat16* asrc1 = h + (size_t)pr1 * DFFN + ksw * 8;
    const __hip_bfloat16* bsrc0 = w2t + (size_t)(colbase + r0) * TW + e * DFFN + ksw * 8;
    const __hip_bfloat16* bsrc1 = bsrc0 + (size_t)16 * TW;

    f32x4 acc[4][4] = {};
    GEMM_LOOP(DFFN / BK9)

    int colg = colbase + wn * 64;
#pragma unroll
    for (int m = 0; m < 4; m++) {
#pragma unroll
        for (int j = 0; j < 4; j++) {
            int r = wm * 64 + m * 16 + kq * 4 + j;
            if (r < rows_e) {
                size_t p = (size_t)off_e + rowbase + r;
                int tok = token_list[p] >> 1;
#pragma unroll
                for (int n = 0; n < 4; n++)
                    atomicAdd(&out[(size_t)tok * NE + colg + n * 16 + rr],
                              acc[m][n][j]);
            }
        }
    }
}

// ---------------------------------------------------------------------------
extern "C" void kernel_launch(void* const* d_in, const int* in_sizes, int n_in,
                              void* d_out, int out_size, void* d_ws, size_t ws_size,
                              hipStream_t stream)
{
    const float* x  = (const float*)d_in[0];
    const float* wr = (const float*)d_in[1];
    const float* w1 = (const float*)d_in[2];
    const float* w2 = (const float*)d_in[3];
    float* out = (float*)d_out;

    // workspace layout (~151.5 MB)
    char* ws = (char*)d_ws;
    size_t o = 0;
    __hip_bfloat16* h   = (__hip_bfloat16*)(ws + o); o += (size_t)P_TOT * DFFN * 2;  // 67.1MB
    __hip_bfloat16* xb  = (__hip_bfloat16*)(ws + o); o += (size_t)T_TOK * NE * 2;    // 16.8MB
    __hip_bfloat16* w1t = (__hip_bfloat16*)(ws + o); o += (size_t)NE * TW * 2;       // 33.6MB  [TW][NE]
    __hip_bfloat16* w2t = (__hip_bfloat16*)(ws + o); o += (size_t)TW * NE * 2;       // 33.6MB  [NE][TW]
    int*   sel_idx    = (int*)(ws + o);   o += P_TOT * 4;
    float* sel_wt     = (float*)(ws + o); o += P_TOT * 4;
    int*   token_list = (int*)(ws + o);   o += P_TOT * 4;
    int*   cnt        = (int*)(ws + o);   o += 64;
    int*   off        = (int*)(ws + o);   o += 64;
    int*   cursor     = (int*)(ws + o);   o += 64;
    int*   tile_tab   = (int*)(ws + o);   o += 256 * 4;
    int*   tile_n     = (int*)(ws + o);   o += 64;
    float* z_part     = (float*)(ws + o); o += 256 * 4;
    float* p_part     = (float*)(ws + o); o += 256 * N_EXP * 4;

    hipMemsetAsync(d_out, 0, (size_t)out_size * sizeof(float), stream);

    cvt_x_kernel<<<T_TOK * NE / 4 / 256, 256, 0, stream>>>(x, (unsigned short*)xb);
    transpose_bf16_kernel<<<dim3(TW / 64, NE / 64), 256, 0, stream>>>(
        w1, (unsigned short*)w1t, NE, TW);     // w1 [NE][TW] -> w1t [TW][NE]
    transpose_bf16_kernel<<<dim3(NE / 64, TW / 64), 256, 0, stream>>>(
        w2, (unsigned short*)w2t, TW, NE);     // w2 [TW][NE] -> w2t [NE][TW]

    router_kernel<<<256, 256, 0, stream>>>(x, wr, sel_idx, sel_wt, z_part, p_part);
    finalize_router<<<1, 256, 0, stream>>>(sel_idx, z_part, p_part, cnt, off, cursor,
                                           tile_tab, tile_n, out);
    scatter_kernel<<<64, 256, 0, stream>>>(sel_idx, off, cursor, token_list);

    // row-tiles of 128: sum_e ceil(cnt_e/128) <= 128 + 7 = 135 -> grid.x = 136
    gemm1_mfma<<<dim3(136, DFFN / BNT), 256, 0, stream>>>(
        xb, w1t, token_list, sel_wt, cnt, off, tile_tab, tile_n, h);
    gemm2_mfma<<<dim3(136, NE / BNT), 256, 0, stream>>>(
        h, w2t, token_list, cnt, off, tile_tab, tile_n, out);
}

// Round 10
// 441.186 us; speedup vs baseline: 1.3956x; 1.0324x over previous
//
#include <hip/hip_runtime.h>
#include <hip/hip_bf16.h>
#include <math.h>

#define T_TOK 8192
#define NE 1024
#define N_EXP 8
#define DFFN 2048
#define TW 16384        // total width = 8*2048
#define P_TOT 16384     // T_TOK * 2

#define BMT 128
#define BNT 128
#define BK9 32

typedef __attribute__((ext_vector_type(8))) short bf16x8;
typedef __attribute__((ext_vector_type(4))) float f32x4;

#define GLOAD_LDS16(g, l) __builtin_amdgcn_global_load_lds( \
    (const __attribute__((address_space(1))) void*)(g), \
    (__attribute__((address_space(3))) void*)(l), 16, 0, 0)

static __device__ __forceinline__ unsigned short f2bf(float f) {
    __hip_bfloat16 b = __float2bfloat16(f);
    return *(unsigned short*)&b;
}

// fast gelu: x·sigmoid(1.595769x + 0.071355x³)  (tanh-form, err ~1e-3 rel)
static __device__ __forceinline__ float gelu_fast(float v) {
    float u2 = v * (1.5957691216f + 0.0713548162f * v * v);
    return v / (1.f + __expf(-u2));
}

// ---------------------------------------------------------------------------
// Kernel A: router (+ fused x->bf16 conversion). 8 lanes per token.
// f32 logits (bf16 would flip near-tie top-k).
// ---------------------------------------------------------------------------
__global__ __launch_bounds__(256) void router_kernel(
    const float* __restrict__ x, const float* __restrict__ wr,
    int* __restrict__ sel_idx, float* __restrict__ sel_wt,
    float* __restrict__ z_part, float* __restrict__ p_part,
    unsigned short* __restrict__ xb)
{
    __shared__ float wrs[N_EXP * NE];   // 32 KB
    __shared__ float zred[32];
    __shared__ float pred[32][8];
    int tid = threadIdx.x;
    for (int i = tid; i < N_EXP * NE / 4; i += 256)
        ((float4*)wrs)[i] = ((const float4*)wr)[i];
    __syncthreads();

    int slot = tid >> 3, oct = tid & 7;
    int t = blockIdx.x * 32 + slot;          // 256 blocks x 32 tokens
    float lg[N_EXP];
#pragma unroll
    for (int e = 0; e < N_EXP; e++) lg[e] = 0.f;

    const float4* x4 = (const float4*)(x + (size_t)t * NE) + oct * 32;
    for (int n4 = 0; n4 < 32; n4++) {
        float4 xv = x4[n4];
        ushort4 o;
        o.x = f2bf(xv.x); o.y = f2bf(xv.y); o.z = f2bf(xv.z); o.w = f2bf(xv.w);
        *(ushort4*)&xb[(size_t)t * NE + oct * 128 + n4 * 4] = o;
#pragma unroll
        for (int e = 0; e < N_EXP; e++) {
            const float* w = &wrs[e * NE + oct * 128 + n4 * 4];
            lg[e] += xv.x * w[0] + xv.y * w[1] + xv.z * w[2] + xv.w * w[3];
        }
    }
#pragma unroll
    for (int d = 1; d < 8; d <<= 1)
#pragma unroll
        for (int e = 0; e < N_EXP; e++) lg[e] += __shfl_xor(lg[e], d);

    float m = lg[0];
#pragma unroll
    for (int e = 1; e < N_EXP; e++) m = fmaxf(m, lg[e]);
    float p[N_EXP], s = 0.f;
#pragma unroll
    for (int e = 0; e < N_EXP; e++) { p[e] = expf(lg[e] - m); s += p[e]; }
    float inv = 1.f / s;
#pragma unroll
    for (int e = 0; e < N_EXP; e++) p[e] *= inv;
    float lse = m + logf(s);

    int e0 = 0;
#pragma unroll
    for (int e = 1; e < N_EXP; e++) if (p[e] > p[e0]) e0 = e;
    int e1 = (e0 == 0) ? 1 : 0;
#pragma unroll
    for (int e = 0; e < N_EXP; e++) if (e != e0 && p[e] > p[e1]) e1 = e;

    if (oct == 0) {
        float wn = 1.f / (p[e0] + p[e1]);
        sel_idx[t * 2 + 0] = e0;
        sel_idx[t * 2 + 1] = e1;
        sel_wt[t * 2 + 0] = p[e0] * wn;
        sel_wt[t * 2 + 1] = p[e1] * wn;
        zred[slot] = lse * lse;
#pragma unroll
        for (int e = 0; e < N_EXP; e++) pred[slot][e] = p[e];
    }
    __syncthreads();
    if (tid == 0) {
        float zs = 0.f;
        for (int i = 0; i < 32; i++) zs += zred[i];
        z_part[blockIdx.x] = zs;
        for (int e = 0; e < N_EXP; e++) {
            float ps = 0.f;
            for (int i = 0; i < 32; i++) ps += pred[i][e];
            p_part[blockIdx.x * N_EXP + e] = ps;
        }
    }
}

// ---------------------------------------------------------------------------
// Kernel B: counts (by scan), offsets, cursors, tile table, aux-loss outputs
// ---------------------------------------------------------------------------
__global__ __launch_bounds__(256) void finalize_router(
    const int* __restrict__ sel_idx,
    const float* __restrict__ z_part, const float* __restrict__ p_part,
    int* __restrict__ cnt, int* __restrict__ off, int* __restrict__ cursor,
    int* __restrict__ tile_tab, int* __restrict__ tile_n,
    float* __restrict__ out)
{
    __shared__ int redc[256];
    __shared__ int cnts[N_EXP];
    int tid = threadIdx.x;
    int c[N_EXP];
#pragma unroll
    for (int e = 0; e < N_EXP; e++) c[e] = 0;
    for (int i = tid; i < P_TOT; i += 256) c[sel_idx[i]]++;
#pragma unroll
    for (int e = 0; e < N_EXP; e++) {
        redc[tid] = c[e];
        __syncthreads();
        for (int st = 128; st > 0; st >>= 1) {
            if (tid < st) redc[tid] += redc[tid + st];
            __syncthreads();
        }
        if (tid == 0) cnts[e] = redc[0];
        __syncthreads();
    }
    if (tid == 0) {
        int o = 0;
        int nt = 0;
        for (int e = 0; e < N_EXP; e++) {
            cnt[e] = cnts[e];
            off[e] = o;
            o += cnts[e];
            cursor[e] = 0;
            for (int rb = 0; rb < cnts[e]; rb += BMT)
                tile_tab[nt++] = (e << 20) | rb;
        }
        off[N_EXP] = o;
        tile_n[0] = nt;
        float zs = 0.f;
        for (int b = 0; b < 256; b++) zs += z_part[b];
        float lb = 0.f;
        float* tail = out + (size_t)T_TOK * NE;
        for (int e = 0; e < N_EXP; e++) {
            float ps = 0.f;
            for (int b = 0; b < 256; b++) ps += p_part[b * N_EXP + e];
            float fi = (float)cnts[e] / (float)P_TOT;
            float pi = ps / (float)T_TOK;
            lb += fi * pi;
            tail[2 + e] = fi;
        }
        tail[0] = zs / (float)T_TOK;       // router_z_loss
        tail[1] = 8.f * lb;                // load_balance_loss
    }
}

// ---------------------------------------------------------------------------
// Kernel C: scatter (token,slot) pairs into per-expert lists
// ---------------------------------------------------------------------------
__global__ __launch_bounds__(256) void scatter_kernel(
    const int* __restrict__ sel_idx, const int* __restrict__ off,
    int* __restrict__ cursor, int* __restrict__ token_list)
{
    int i = blockIdx.x * 256 + threadIdx.x;
    if (i < P_TOT) {
        int e = sel_idx[i];
        int pos = atomicAdd(&cursor[e], 1);
        token_list[off[e] + pos] = i;   // token = i>>1, slot = i&1
    }
}

// ---------------------------------------------------------------------------
// Kernel P2: transpose + convert: src [R][C] f32 -> dst [C][R] bf16
// ---------------------------------------------------------------------------
__global__ __launch_bounds__(256) void transpose_bf16_kernel(
    const float* __restrict__ src, unsigned short* __restrict__ dst,
    int R, int C)
{
    __shared__ float tile[64][65];
    int rb = blockIdx.y * 64, cb = blockIdx.x * 64;
    int tid = threadIdx.x;
#pragma unroll
    for (int p = 0; p < 4; p++) {
        int idx = p * 256 + tid;
        int r = idx >> 4, c4 = (idx & 15) << 2;
        float4 v = *(const float4*)&src[(size_t)(rb + r) * C + cb + c4];
        tile[r][c4 + 0] = v.x; tile[r][c4 + 1] = v.y;
        tile[r][c4 + 2] = v.z; tile[r][c4 + 3] = v.w;
    }
    __syncthreads();
#pragma unroll
    for (int p = 0; p < 4; p++) {
        int idx = p * 256 + tid;
        int c = idx >> 4, r4 = (idx & 15) << 2;
        ushort4 o;
        o.x = f2bf(tile[r4 + 0][c]); o.y = f2bf(tile[r4 + 1][c]);
        o.z = f2bf(tile[r4 + 2][c]); o.w = f2bf(tile[r4 + 3][c]);
        *(ushort4*)&dst[(size_t)(cb + c) * R + rb + r4] = o;
    }
}

// ---------------------------------------------------------------------------
// GEMM core (R9 structure: 128x128 tile, BK=32, 4 waves 2x2, acc[4][4],
// 32 KB LDS dbuf, 4 blocks/CU, counted vmcnt(4), zero-conflict XOR swizzle)
// + setprio around the MFMA cluster (cross-block wave role-diversity exists).
// ---------------------------------------------------------------------------
#define STG(buf, kb) do {                                                 \
    GLOAD_LDS16(asrc0 + (kb), &As[buf][wid * 1024]);                      \
    GLOAD_LDS16(asrc1 + (kb), &As[buf][wid * 1024 + 512]);                \
    GLOAD_LDS16(bsrc0 + (kb), &Bs[buf][wid * 1024]);                      \
    GLOAD_LDS16(bsrc1 + (kb), &Bs[buf][wid * 1024 + 512]);                \
} while (0)

#define GEMM_LOOP(NKT)                                                    \
    STG(0, 0);                                                            \
    for (int t = 0; t < (NKT); t++) {                                     \
        int cur = t & 1;                                                  \
        if (t + 1 < (NKT)) {                                              \
            STG(cur ^ 1, (t + 1) * BK9);                                  \
            asm volatile("s_waitcnt vmcnt(4)" ::: "memory");              \
        } else {                                                          \
            asm volatile("s_waitcnt vmcnt(0)" ::: "memory");              \
        }                                                                 \
        __builtin_amdgcn_s_barrier();                                     \
        __builtin_amdgcn_sched_barrier(0);                                \
        bf16x8 af[4], bfr[4];                                             \
        _Pragma("unroll")                                                 \
        for (int m = 0; m < 4; m++)                                       \
            af[m] = *(const bf16x8*)&As[cur][(wm * 64 + m * 16 + rr) * BK9 + kqa * 8]; \
        _Pragma("unroll")                                                 \
        for (int n = 0; n < 4; n++)                                       \
            bfr[n] = *(const bf16x8*)&Bs[cur][(wn * 64 + n * 16 + rr) * BK9 + kqa * 8]; \
        __builtin_amdgcn_s_setprio(1);                                    \
        _Pragma("unroll")                                                 \
        for (int m = 0; m < 4; m++)                                       \
            _Pragma("unroll")                                             \
            for (int n = 0; n < 4; n++)                                   \
                acc[m][n] = __builtin_amdgcn_mfma_f32_16x16x32_bf16(      \
                    af[m], bfr[n], acc[m][n], 0, 0, 0);                   \
        __builtin_amdgcn_s_setprio(0);                                    \
        __builtin_amdgcn_sched_barrier(0);                                \
        __builtin_amdgcn_s_barrier();                                     \
    }

// ---------------------------------------------------------------------------
// Kernel D: grouped GEMM1:  h[p,:] = selw[p] * gelu(xb[tok(p),:] @ W1_e)
// 1-D grid 2176: slot = b&7 pins XCD -> col-tiles {2*slot, 2*slot+1};
// idx = b>>3: col = 2*slot + (idx&1), row-tile = idx>>1 (A-tile reused by
// consecutive idx pair; expert-major tile_tab keeps hot B ~512 KB in L2).
// ---------------------------------------------------------------------------
__global__ __launch_bounds__(256, 4) void gemm1_mfma(
    const __hip_bfloat16* __restrict__ xb, const __hip_bfloat16* __restrict__ w1t,
    const int* __restrict__ token_list, const float* __restrict__ sel_wt,
    const int* __restrict__ cnt, const int* __restrict__ off,
    const int* __restrict__ tile_tab, const int* __restrict__ tile_n,
    __hip_bfloat16* __restrict__ h)
{
    __shared__ __align__(16) __hip_bfloat16 As[2][BMT * BK9];   // 16 KB
    __shared__ __align__(16) __hip_bfloat16 Bs[2][BNT * BK9];   // 16 KB

    int b = blockIdx.x;
    int slot = b & 7, idx = b >> 3;
    int rowt = idx >> 1;
    if (rowt >= tile_n[0]) return;
    int colbase = (slot * 2 + (idx & 1)) * BNT;
    int tab = tile_tab[rowt];
    int e = tab >> 20, rowbase = tab & 0xFFFFF;
    int off_e = off[e];
    int rows_e = cnt[e] - rowbase;

    int tid = threadIdx.x;
    int wid = tid >> 6, lane = tid & 63;
    int wm = wid >> 1, wn = wid & 1;
    int rr = lane & 15, kq = lane >> 4;
    int kqa = kq ^ ((rr >> 1) & 3);
    int ksw = (lane & 3) ^ ((lane >> 3) & 3);

    int r0 = wid * 32 + (lane >> 2);
    int r1 = r0 + 16;
    int ent0 = token_list[off_e + rowbase + ((r0 < rows_e) ? r0 : 0)];
    int ent1 = token_list[off_e + rowbase + ((r1 < rows_e) ? r1 : 0)];
    const __hip_bfloat16* asrc0 = xb + (size_t)(ent0 >> 1) * NE + ksw * 8;
    const __hip_bfloat16* asrc1 = xb + (size_t)(ent1 >> 1) * NE + ksw * 8;
    const __hip_bfloat16* bsrc0 = w1t + (size_t)(e * DFFN + colbase + r0) * NE + ksw * 8;
    const __hip_bfloat16* bsrc1 = bsrc0 + (size_t)16 * NE;

    f32x4 acc[4][4] = {};
    GEMM_LOOP(NE / BK9)

    int colg = colbase + wn * 64;
#pragma unroll
    for (int m = 0; m < 4; m++) {
#pragma unroll
        for (int j = 0; j < 4; j++) {
            int r = wm * 64 + m * 16 + kq * 4 + j;
            if (r < rows_e) {
                size_t p = (size_t)off_e + rowbase + r;
                float wgt = sel_wt[token_list[p]];
#pragma unroll
                for (int n = 0; n < 4; n++) {
                    float g = gelu_fast(acc[m][n][j]);
                    h[p * DFFN + colg + n * 16 + rr] = __float2bfloat16(wgt * g);
                }
            }
        }
    }
}

// ---------------------------------------------------------------------------
// Kernel E: grouped GEMM2:  out[tok(p),:] += h[p,:] @ W2_e  (atomic f32;
// exactly 2 commutative addends per element -> deterministic).
// 1-D grid 1088: slot = b&7 -> col-tile slot (XCD-pinned B panel),
// row-tile = b>>3.
// ---------------------------------------------------------------------------
__global__ __launch_bounds__(256, 4) void gemm2_mfma(
    const __hip_bfloat16* __restrict__ h, const __hip_bfloat16* __restrict__ w2t,
    const int* __restrict__ token_list,
    const int* __restrict__ cnt, const int* __restrict__ off,
    const int* __restrict__ tile_tab, const int* __restrict__ tile_n,
    float* __restrict__ out)
{
    __shared__ __align__(16) __hip_bfloat16 As[2][BMT * BK9];
    __shared__ __align__(16) __hip_bfloat16 Bs[2][BNT * BK9];

    int b = blockIdx.x;
    int slot = b & 7, rowt = b >> 3;
    if (rowt >= tile_n[0]) return;
    int colbase = slot * BNT;
    int tab = tile_tab[rowt];
    int e = tab >> 20, rowbase = tab & 0xFFFFF;
    int off_e = off[e];
    int rows_e = cnt[e] - rowbase;

    int tid = threadIdx.x;
    int wid = tid >> 6, lane = tid & 63;
    int wm = wid >> 1, wn = wid & 1;
    int rr = lane & 15, kq = lane >> 4;
    int kqa = kq ^ ((rr >> 1) & 3);
    int ksw = (lane & 3) ^ ((lane >> 3) & 3);

    int r0 = wid * 32 + (lane >> 2);
    int r1 = r0 + 16;
    int pr0 = off_e + rowbase + ((r0 < rows_e) ? r0 : 0);
    int pr1 = off_e + rowbase + ((r1 < rows_e) ? r1 : 0);
    const __hip_bfloat16* asrc0 = h + (size_t)pr0 * DFFN + ksw * 8;
    const __hip_bfloat16* asrc1 = h + (size_t)pr1 * DFFN + ksw * 8;
    const __hip_bfloat16* bsrc0 = w2t + (size_t)(colbase + r0) * TW + e * DFFN + ksw * 8;
    const __hip_bfloat16* bsrc1 = bsrc0 + (size_t)16 * TW;

    f32x4 acc[4][4] = {};
    GEMM_LOOP(DFFN / BK9)

    int colg = colbase + wn * 64;
#pragma unroll
    for (int m = 0; m < 4; m++) {
#pragma unroll
        for (int j = 0; j < 4; j++) {
            int r = wm * 64 + m * 16 + kq * 4 + j;
            if (r < rows_e) {
                size_t p = (size_t)off_e + rowbase + r;
                int tok = token_list[p] >> 1;
#pragma unroll
                for (int n = 0; n < 4; n++)
                    atomicAdd(&out[(size_t)tok * NE + colg + n * 16 + rr],
                              acc[m][n][j]);
            }
        }
    }
}

// ---------------------------------------------------------------------------
extern "C" void kernel_launch(void* const* d_in, const int* in_sizes, int n_in,
                              void* d_out, int out_size, void* d_ws, size_t ws_size,
                              hipStream_t stream)
{
    const float* x  = (const float*)d_in[0];
    const float* wr = (const float*)d_in[1];
    const float* w1 = (const float*)d_in[2];
    const float* w2 = (const float*)d_in[3];
    float* out = (float*)d_out;

    // workspace layout (~151.5 MB)
    char* ws = (char*)d_ws;
    size_t o = 0;
    __hip_bfloat16* h   = (__hip_bfloat16*)(ws + o); o += (size_t)P_TOT * DFFN * 2;  // 67.1MB
    __hip_bfloat16* xb  = (__hip_bfloat16*)(ws + o); o += (size_t)T_TOK * NE * 2;    // 16.8MB
    __hip_bfloat16* w1t = (__hip_bfloat16*)(ws + o); o += (size_t)NE * TW * 2;       // 33.6MB  [TW][NE]
    __hip_bfloat16* w2t = (__hip_bfloat16*)(ws + o); o += (size_t)TW * NE * 2;       // 33.6MB  [NE][TW]
    int*   sel_idx    = (int*)(ws + o);   o += P_TOT * 4;
    float* sel_wt     = (float*)(ws + o); o += P_TOT * 4;
    int*   token_list = (int*)(ws + o);   o += P_TOT * 4;
    int*   cnt        = (int*)(ws + o);   o += 64;
    int*   off        = (int*)(ws + o);   o += 64;
    int*   cursor     = (int*)(ws + o);   o += 64;
    int*   tile_tab   = (int*)(ws + o);   o += 256 * 4;
    int*   tile_n     = (int*)(ws + o);   o += 64;
    float* z_part     = (float*)(ws + o); o += 256 * 4;
    float* p_part     = (float*)(ws + o); o += 256 * N_EXP * 4;

    hipMemsetAsync(d_out, 0, (size_t)out_size * sizeof(float), stream);

    router_kernel<<<256, 256, 0, stream>>>(x, wr, sel_idx, sel_wt, z_part, p_part,
                                           (unsigned short*)xb);
    transpose_bf16_kernel<<<dim3(TW / 64, NE / 64), 256, 0, stream>>>(
        w1, (unsigned short*)w1t, NE, TW);     // w1 [NE][TW] -> w1t [TW][NE]
    transpose_bf16_kernel<<<dim3(NE / 64, TW / 64), 256, 0, stream>>>(
        w2, (unsigned short*)w2t, TW, NE);     // w2 [TW][NE] -> w2t [NE][TW]
    finalize_router<<<1, 256, 0, stream>>>(sel_idx, z_part, p_part, cnt, off, cursor,
                                           tile_tab, tile_n, out);
    scatter_kernel<<<64, 256, 0, stream>>>(sel_idx, off, cursor, token_list);

    // gemm1: 8 XCD-slots x (136 row-tiles x 2 cols) = 2176 blocks
    gemm1_mfma<<<2176, 256, 0, stream>>>(
        xb, w1t, token_list, sel_wt, cnt, off, tile_tab, tile_n, h);
    // gemm2: 8 XCD-slots x 136 row-tiles = 1088 blocks
    gemm2_mfma<<<1088, 256, 0, stream>>>(
        h, w2t, token_list, cnt, off, tile_tab, tile_n, out);
}